// Round 5
// baseline (2424.985 us; speedup 1.0000x reference)
//
#include <hip/hip_runtime.h>

// File-scope: forbid implicit fma contraction (keeps every a*b+c as two
// single-rounded IEEE ops, matching the numpy reference bit-for-bit).
#pragma clang fp contract(off)

#define NPOINT 2048
#define NSAMPLE 32
#define NPTS 8192
#define NB 4
#define CH 16
#define FPS_THREADS 512
#define PTS_PER_THREAD (NPTS / FPS_THREADS) /* 16 */
#define PAIRS (PTS_PER_THREAD / 2)          /* 8 */
#define FPS_WAVES (FPS_THREADS / 64)        /* 8 */

typedef unsigned long long u64;
typedef float v2f __attribute__((ext_vector_type(2)));

// Output layout (flat float32, concatenated in reference return order)
#define OFF_NEWXYZ 0
#define OFF_NEWPTS (NB * NPOINT * 3)                          /* 24576 */
#define OFF_IDX (OFF_NEWPTS + NB * NPOINT * NSAMPLE * CH)     /* 4218880 */
#define OFF_GXYZ (OFF_IDX + NB * NPOINT * NSAMPLE)            /* 4481024 */

template <int CTRL>
__device__ __forceinline__ float dpp_fmax(float v) {
  // bound_ctrl=true -> 0-fill; distances are >= 0 so 0 is a safe identity.
  int o = __builtin_amdgcn_update_dpp(0, __float_as_int(v), CTRL, 0xf, 0xf, true);
  return fmaxf(v, __int_as_float(o));
}

// ---------------- FPS: one block per batch, sequential 2048-step scan ------
// Reference semantics: idxs[0]=0; each step: dists=min(dists,|p-p_last|^2),
// next = argmax(dists) with FIRST-index tie-break. Op order mirrored:
// (dx*dx + dy*dy) + dz*dz, single-rounded IEEE, no fma contraction.
//
// R22: coords-ride-the-keys, v2. The serial head chain was
// barrier -> key ds_read(~140cy) -> u64 tree(~30cy) -> DEPENDENT
// lpxyz[gi] ds_read(~140cy). Remove the second hop:
//  - post-loop, each lane speculatively reads lpxyz[besti] (its OWN
//    candidate; latency hides under the DPP/ballot tail); the winner lane
//    publishes those coords (b128) beside its key.
//  - head issues key reads + all 8 coord-slot reads in one window (LDS
//    returns in order -> tree overlaps coord returns), then a 7x float4
//    cndmask tree picks the winner's coords via ws = gi>>10 (contiguous
//    ownership). ~42cy issue replaces ~140cy serial latency.
// Lessons applied: inner loop BYTE-IDENTICAL to the 1735us R17 form (R21:
// in-loop asm broke scheduling); NO in-loop coord tracking and lpxyz kept
// (R20: +state -> VGPR 60 / AGPR churn, +1100us); 512t / 2 waves per SIMD
// (R19: 1 wave exposes all latency). VGPR alarm bounds: <88 or >128.
// Tie-breaks (exact jnp.argmax lowest-index): parity checks .x first; strict
// '>' keeps lowest jp; ballot-ctz keeps lowest lane; key low word (8191-idx)
// keeps lowest wave. Contiguous ownership (thread t owns t*16..t*16+15)
// keeps (wave,lane,j) order == global index order. Keys are globally unique
// (idx in low bits) so the u64 max has no cross-wave ties.
__global__ __launch_bounds__(FPS_THREADS)
__attribute__((amdgpu_waves_per_eu(2))) void fps_kernel(
    const float* __restrict__ in, float* __restrict__ out) {
  __shared__ float4 lpxyz[NPTS];      // 128 KB; speculative candidate reads
  __shared__ float newb[NPOINT * 3];  // 24 KB newxyz staging
  __shared__ alignas(16) u64 slots[2][FPS_WAVES];      // per-wave argmax keys
  __shared__ alignas(16) float4 slots_c[2][FPS_WAVES]; // per-wave winner coords

  const int b = blockIdx.x;
  const int tid = threadIdx.x;
  const int lane = tid & 63;
  const int wv = tid >> 6;
  const float* base = in + (size_t)b * NPTS * CH;

  v2f pxv[PAIRS], pyv[PAIRS], pzv[PAIRS], dv[PAIRS];
#pragma unroll
  for (int jp = 0; jp < PAIRS; ++jp) {
    int p0 = tid * PTS_PER_THREAD + 2 * jp;
    float4 r0 = *reinterpret_cast<const float4*>(base + (size_t)p0 * CH);
    float4 r1 = *reinterpret_cast<const float4*>(base + (size_t)(p0 + 1) * CH);
    pxv[jp] = (v2f){r0.x, r1.x};
    pyv[jp] = (v2f){r0.y, r1.y};
    pzv[jp] = (v2f){r0.z, r1.z};
    lpxyz[p0] = r0;
    lpxyz[p0 + 1] = r1;
    dv[jp] = (v2f){__builtin_inff(), __builtin_inff()};
  }
  // Prime parity-0 slots: slot 0 = (+inf, idx 0) wins the first compare; its
  // coords are point 0's. Dummy slots (key 0) can never win vs +inf.
  if (tid < FPS_WAVES) {
    slots[0][tid] = (tid == 0) ? (((u64)0x7f800000u << 32) | 8191u) : 0ull;
    slots_c[0][tid] = make_float4(0.f, 0.f, 0.f, 0.f);
    slots_c[1][tid] = make_float4(0.f, 0.f, 0.f, 0.f);
  }
  if (tid == 0)
    slots_c[0][0] = make_float4(base[0], base[1], base[2], 0.f);

  for (int it = 0; it < NPOINT; ++it) {
    __syncthreads();  // separates slot writes (it-1) from reads (it)
    const int par = it & 1;
    // Keys (4x b128) + all 8 coord slots (8x b128): one latency window.
    // LDS returns in issue order -> the key tree overlaps coord returns.
    const ulonglong2* sp = reinterpret_cast<const ulonglong2*>(&slots[par][0]);
    const ulonglong2 s01 = sp[0];
    const ulonglong2 s23 = sp[1];
    const ulonglong2 s45 = sp[2];
    const ulonglong2 s67 = sp[3];
    const float4 c0 = slots_c[par][0];
    const float4 c1 = slots_c[par][1];
    const float4 c2 = slots_c[par][2];
    const float4 c3 = slots_c[par][3];
    const float4 c4 = slots_c[par][4];
    const float4 c5 = slots_c[par][5];
    const float4 c6 = slots_c[par][6];
    const float4 c7 = slots_c[par][7];
    // 7-compare u64 max (keys globally unique -> no ties).
    u64 ka = (s01.y > s01.x) ? s01.y : s01.x;
    u64 kb = (s23.y > s23.x) ? s23.y : s23.x;
    u64 kc = (s45.y > s45.x) ? s45.y : s45.x;
    u64 kd = (s67.y > s67.x) ? s67.y : s67.x;
    ka = (kb > ka) ? kb : ka;
    kc = (kd > kc) ? kd : kc;
    const u64 k = (kc > ka) ? kc : ka;
    const unsigned gi = 8191u - (unsigned)k;  // low 32 bits = 8191-idx
    // Winner coords: 3-level cndmask tree on the owner-wave index.
    const unsigned ws = gi >> 10;  // 1024 points per wave
    const bool b0 = (ws & 1u) != 0u;
    const bool b1 = (ws & 2u) != 0u;
    const bool b2 = (ws & 4u) != 0u;
    const float4 s0 = b0 ? c1 : c0;
    const float4 s1 = b0 ? c3 : c2;
    const float4 s2 = b0 ? c5 : c4;
    const float4 s3 = b0 ? c7 : c6;
    const float4 t0 = b1 ? s1 : s0;
    const float4 t1 = b1 ? s3 : s2;
    const float gx = b2 ? t1.x : t0.x;
    const float gy = b2 ? t1.y : t0.y;
    const float gz = b2 ? t1.z : t0.z;
    if (tid == 0) {
      newb[it * 3 + 0] = gx;
      newb[it * 3 + 1] = gy;
      newb[it * 3 + 2] = gz;
    }
    if (it == NPOINT - 1) break;  // last winner staged; update/publish useless
    // Distance update: BYTE-IDENTICAL structure to the verified 1735us loop.
    // nb = max3(dn.x, dn.y, bestv): (nb > bestv) == (fmax(dn.x,dn.y) > bestv)
    // exactly, and bestv=nb is the same value.
    float bestv = -1.0f;
    float bestx = -1.0f;
    int bestjp = 0;
#pragma unroll
    for (int jp = 0; jp < PAIRS; ++jp) {
      v2f dx = pxv[jp] - gx;
      v2f dy = pyv[jp] - gy;
      v2f dz = pzv[jp] - gz;
      v2f nd = (dx * dx + dy * dy) + dz * dz;
      v2f dn = {fminf(dv[jp].x, nd.x), fminf(dv[jp].y, nd.y)};
      dv[jp] = dn;
      float nb = fmaxf(fmaxf(dn.x, dn.y), bestv);  // -> v_max3_f32
      bool t = nb > bestv;  // strict: lowest jp wins ties
      bestjp = t ? jp : bestjp;
      bestx = t ? dn.x : bestx;
      bestv = nb;
    }
    // Within-pair parity: .x first (lower index) on ties.
    const int bestj = 2 * bestjp + ((bestx == bestv) ? 0 : 1);
    const unsigned besti = (unsigned)(tid * PTS_PER_THREAD + bestj);
    // Speculative per-lane candidate coords (latency hides under DPP tail).
    const float4 cand = lpxyz[besti];
    // Wave max via 6 DPP rounds -> lane 63; ballot -> lowest matching lane.
    float wm = bestv;
    wm = dpp_fmax<0x111>(wm);  // row_shr:1
    wm = dpp_fmax<0x112>(wm);  // row_shr:2
    wm = dpp_fmax<0x114>(wm);  // row_shr:4
    wm = dpp_fmax<0x118>(wm);  // row_shr:8
    wm = dpp_fmax<0x142>(wm);  // row_bcast15
    wm = dpp_fmax<0x143>(wm);  // row_bcast31
    const float swm =
        __int_as_float(__builtin_amdgcn_readlane(__float_as_int(wm), 63));
    const u64 wbal = __ballot(bestv == swm);
    const int wl = (int)__builtin_ctzll(wbal);
    if (lane == wl) {  // tiny tail: key b64 + coords b128
      slots[par ^ 1][wv] =
          ((u64)__float_as_uint(bestv) << 32) | (8191u - besti);
      slots_c[par ^ 1][wv] = cand;
    }
  }
  __syncthreads();
  // Dump staged newxyz to global once.
  float* ob = out + OFF_NEWXYZ + (size_t)b * NPOINT * 3;
  for (int i = tid; i < NPOINT * 3; i += FPS_THREADS) ob[i] = newb[i];
}

// ---------------- Ball query + group: one wave per query -------------------
__device__ __forceinline__ void write_slot(float* __restrict__ out,
                                           const float* __restrict__ base,
                                           int b, int qi, int s, int p,
                                           float4 r0, float qx, float qy,
                                           float qz) {
  float dx = __fsub_rn(r0.x, qx);
  float dy = __fsub_rn(r0.y, qy);
  float dz = __fsub_rn(r0.z, qz);
  size_t qs = (size_t)b * NPOINT + qi;
  out[OFF_IDX + qs * NSAMPLE + s] = (float)p;  // idx stored as float32
  float* g = out + OFF_GXYZ + (qs * NSAMPLE + s) * 3;
  g[0] = dx;
  g[1] = dy;
  g[2] = dz;
  const float* row = base + (size_t)p * CH;
  float4 r1 = *reinterpret_cast<const float4*>(row + 4);
  float4 r2 = *reinterpret_cast<const float4*>(row + 8);
  float4 r3 = *reinterpret_cast<const float4*>(row + 12);
  float* np_ = out + OFF_NEWPTS + (qs * NSAMPLE + s) * CH;
  *reinterpret_cast<float4*>(np_ + 0) = make_float4(dx, dy, dz, r0.w);
  *reinterpret_cast<float4*>(np_ + 4) = r1;
  *reinterpret_cast<float4*>(np_ + 8) = r2;
  *reinterpret_cast<float4*>(np_ + 12) = r3;
}

__global__ __launch_bounds__(256) void ballq_kernel(
    const float* __restrict__ in, float* __restrict__ out) {
  const int lane = threadIdx.x & 63;
  const int qid = blockIdx.x * 4 + (threadIdx.x >> 6);
  const int b = qid >> 11;    // / NPOINT
  const int qi = qid & 2047;  // % NPOINT
  const float* base = in + (size_t)b * NPTS * CH;
  const float* q = out + OFF_NEWXYZ + ((size_t)b * NPOINT + qi) * 3;
  float qx = q[0], qy = q[1], qz = q[2];
  // Mirror reference: d2 = sum(q*q) + sum(p*p) - 2*(q . p)
  float qn = __fadd_rn(__fadd_rn(__fmul_rn(qx, qx), __fmul_rn(qy, qy)),
                       __fmul_rn(qz, qz));

  int cnt = 0;
  int first = 0;
  bool have_first = false;
  for (int chunk = 0; chunk < NPTS / 64 && cnt < NSAMPLE; ++chunk) {
    int p = chunk * 64 + lane;
    float4 r0 = *reinterpret_cast<const float4*>(base + (size_t)p * CH);
    float pn =
        __fadd_rn(__fadd_rn(__fmul_rn(r0.x, r0.x), __fmul_rn(r0.y, r0.y)),
                  __fmul_rn(r0.z, r0.z));
    float dot =
        __fadd_rn(__fadd_rn(__fmul_rn(qx, r0.x), __fmul_rn(qy, r0.y)),
                  __fmul_rn(qz, r0.z));
    float d2 = __fsub_rn(__fadd_rn(qn, pn), __fmul_rn(2.0f, dot));
    bool in_r = d2 < 1.0f;  // RADIUS^2
    unsigned long long mask = __ballot(in_r);
    if (!have_first && mask) {
      first = chunk * 64 + __builtin_ctzll(mask);
      have_first = true;
    }
    int pos = cnt + __popcll(mask & ((1ull << lane) - 1ull));
    if (in_r && pos < NSAMPLE) write_slot(out, base, b, qi, pos, p, r0, qx, qy, qz);
    cnt += __popcll(mask);
  }
  if (cnt < NSAMPLE) {
    // Pad remaining slots with the first in-radius index (reference fill rule).
    int s = cnt + lane;
    if (s < NSAMPLE) {
      float4 r0 = *reinterpret_cast<const float4*>(base + (size_t)first * CH);
      write_slot(out, base, b, qi, s, first, r0, qx, qy, qz);
    }
  }
}

extern "C" void kernel_launch(void* const* d_in, const int* in_sizes, int n_in,
                              void* d_out, int out_size, void* d_ws,
                              size_t ws_size, hipStream_t stream) {
  (void)in_sizes;
  (void)n_in;
  (void)out_size;
  (void)d_ws;
  (void)ws_size;
  const float* in = (const float*)d_in[0];
  float* out = (float*)d_out;
  fps_kernel<<<NB, FPS_THREADS, 0, stream>>>(in, out);
  ballq_kernel<<<(NB * NPOINT) / 4, 256, 0, stream>>>(in, out);
}

// Round 6
// 1839.844 us; speedup vs baseline: 1.3180x; 1.3180x over previous
//
#include <hip/hip_runtime.h>

// File-scope: forbid implicit fma contraction (keeps every a*b+c as two
// single-rounded IEEE ops, matching the numpy reference bit-for-bit).
#pragma clang fp contract(off)

#define NPOINT 2048
#define NSAMPLE 32
#define NPTS 8192
#define NB 4
#define CH 16
#define FPS_THREADS 512
#define PTS_PER_THREAD (NPTS / FPS_THREADS) /* 16 */
#define PAIRS (PTS_PER_THREAD / 2)          /* 8 */
#define FPS_WAVES (FPS_THREADS / 64)        /* 8 */

typedef unsigned long long u64;
typedef float v2f __attribute__((ext_vector_type(2)));

// Output layout (flat float32, concatenated in reference return order)
#define OFF_NEWXYZ 0
#define OFF_NEWPTS (NB * NPOINT * 3)                          /* 24576 */
#define OFF_IDX (OFF_NEWPTS + NB * NPOINT * NSAMPLE * CH)     /* 4218880 */
#define OFF_GXYZ (OFF_IDX + NB * NPOINT * NSAMPLE)            /* 4481024 */

template <int CTRL>
__device__ __forceinline__ float dpp_fmax(float v) {
  // bound_ctrl=true -> 0-fill; distances are >= 0 so 0 is a safe identity.
  int o = __builtin_amdgcn_update_dpp(0, __float_as_int(v), CTRL, 0xf, 0xf, true);
  return fmaxf(v, __int_as_float(o));
}

// ---------------- FPS: one block per batch, sequential 2048-step scan ------
// Reference semantics: idxs[0]=0; each step: dists=min(dists,|p-p_last|^2),
// next = argmax(dists) with FIRST-index tie-break. Op order mirrored:
// (dx*dx + dy*dy) + dz*dz, single-rounded IEEE, no fma contraction.
//
// R23: fps RESTORED BYTE-FOR-BYTE to the verified 1739us form (Round 0).
// Session ledger on this structure — all perturbations regressed:
//   R18 spin-poll slots        +152us (poll issue + s_sleep quantization)
//   R19 256t / 1 wave/SIMD     +385us (latency exposed, VGPR squeeze)
//   R20 coords+in-loop track  +1100us (VGPR 88->60, AGPR churn)
//   R21 inline-asm pk loop     +410us (asm broke scheduler interleave;
//                                      busy-TIME flat -> loop was already
//                                      packed; VALUBusy formula 2x on SIMD-32)
//   R22 coords-ride-keys       +620us (publish waits on speculative read;
//                                      +27 cndmask in head)
// Conclusion: 512t / 2 waves/SIMD / lpxyz LDS / key-slot exchange / one
// barrier/iter + this exact loop body is a strong local optimum (~37% true
// issue, convoy-bound, but every instruction-stream perturbation loses more
// to scheduling than it saves in latency). DO NOT TOUCH.
// Tie-breaks (exact jnp.argmax lowest-index): parity checks .x first; strict
// '>' keeps lowest jp; ballot-ctz keeps lowest lane; key low word (8191-idx)
// keeps lowest wave. Contiguous ownership (thread t owns t*16..t*16+15)
// keeps (wave,lane,j) order == global index order.
__global__ __launch_bounds__(FPS_THREADS)
__attribute__((amdgpu_waves_per_eu(2))) void fps_kernel(
    const float* __restrict__ in, float* __restrict__ out) {
  __shared__ float4 lpxyz[NPTS];      // 128 KB; winner coords: 1 ds_read_b128
  __shared__ float newb[NPOINT * 3];  // 24 KB newxyz staging
  __shared__ alignas(16) u64 slots[2][FPS_WAVES];  // per-wave argmax keys

  const int b = blockIdx.x;
  const int tid = threadIdx.x;
  const int lane = tid & 63;
  const int wv = tid >> 6;
  const float* base = in + (size_t)b * NPTS * CH;

  v2f pxv[PAIRS], pyv[PAIRS], pzv[PAIRS], dv[PAIRS];
#pragma unroll
  for (int jp = 0; jp < PAIRS; ++jp) {
    int p0 = tid * PTS_PER_THREAD + 2 * jp;
    float4 r0 = *reinterpret_cast<const float4*>(base + (size_t)p0 * CH);
    float4 r1 = *reinterpret_cast<const float4*>(base + (size_t)(p0 + 1) * CH);
    pxv[jp] = (v2f){r0.x, r1.x};
    pyv[jp] = (v2f){r0.y, r1.y};
    pzv[jp] = (v2f){r0.z, r1.z};
    lpxyz[p0] = r0;
    lpxyz[p0 + 1] = r1;
    dv[jp] = (v2f){__builtin_inff(), __builtin_inff()};
  }
  // Prime parity-0 slots: slot 0 = (+inf, idx 0) wins the first compare.
  if (tid < FPS_WAVES)
    slots[0][tid] = (tid == 0) ? (((u64)0x7f800000u << 32) | 8191u) : 0ull;

  for (int it = 0; it < NPOINT; ++it) {
    __syncthreads();  // separates slot writes (it-1) from reads (it)
    // Read all 8 wave keys (broadcast, 4x ds_read_b128), 7-compare u64 max.
    const ulonglong2* sp =
        reinterpret_cast<const ulonglong2*>(&slots[it & 1][0]);
    const ulonglong2 s01 = sp[0];
    const ulonglong2 s23 = sp[1];
    const ulonglong2 s45 = sp[2];
    const ulonglong2 s67 = sp[3];
    u64 ka = (s01.y > s01.x) ? s01.y : s01.x;
    u64 kb = (s23.y > s23.x) ? s23.y : s23.x;
    u64 kc = (s45.y > s45.x) ? s45.y : s45.x;
    u64 kd = (s67.y > s67.x) ? s67.y : s67.x;
    ka = (kb > ka) ? kb : ka;
    kc = (kd > kc) ? kd : kc;
    const u64 k = (kc > ka) ? kc : ka;
    const int gi = 8191 - (int)(unsigned)k;  // low 32 bits = 8191-idx
    // Winner coords: broadcast LDS read.
    const float4 g = lpxyz[gi];
    const float gx = g.x, gy = g.y, gz = g.z;
    if (tid == 0) {
      newb[it * 3 + 0] = gx;
      newb[it * 3 + 1] = gy;
      newb[it * 3 + 2] = gz;
    }
    // Distance update (packed pairs; exact IEEE per-element) + in-loop
    // pair-granular tracking (bestjp + bestx; hidden under loop ILP).
    float bestv = -1.0f;
    float bestx = -1.0f;
    int bestjp = 0;
#pragma unroll
    for (int jp = 0; jp < PAIRS; ++jp) {
      v2f dx = pxv[jp] - gx;
      v2f dy = pyv[jp] - gy;
      v2f dz = pzv[jp] - gz;
      v2f nd = (dx * dx + dy * dy) + dz * dz;
      v2f dn = {fminf(dv[jp].x, nd.x), fminf(dv[jp].y, nd.y)};
      dv[jp] = dn;
      float pm = fmaxf(dn.x, dn.y);
      bool t = pm > bestv;  // strict: lowest jp wins ties
      bestjp = t ? jp : bestjp;
      bestx = t ? dn.x : bestx;
      bestv = fmaxf(bestv, pm);
    }
    // Within-pair parity: .x first (lower index) on ties.
    const int bestj = 2 * bestjp + ((bestx == bestv) ? 0 : 1);
    const unsigned besti = (unsigned)(tid * PTS_PER_THREAD + bestj);
    // Wave max via 6 DPP rounds -> lane 63; ballot -> lowest matching lane.
    float wm = bestv;
    wm = dpp_fmax<0x111>(wm);  // row_shr:1
    wm = dpp_fmax<0x112>(wm);  // row_shr:2
    wm = dpp_fmax<0x114>(wm);  // row_shr:4
    wm = dpp_fmax<0x118>(wm);  // row_shr:8
    wm = dpp_fmax<0x142>(wm);  // row_bcast15
    wm = dpp_fmax<0x143>(wm);  // row_bcast31
    const float swm =
        __int_as_float(__builtin_amdgcn_readlane(__float_as_int(wm), 63));
    const u64 wbal = __ballot(bestv == swm);
    const int wl = (int)__builtin_ctzll(wbal);
    if (lane == wl) {  // tiny tail: pack + one ds_write_b64
      slots[(it + 1) & 1][wv] =
          ((u64)__float_as_uint(bestv) << 32) | (8191u - besti);
    }
  }
  __syncthreads();
  // Dump staged newxyz to global once.
  float* ob = out + OFF_NEWXYZ + (size_t)b * NPOINT * 3;
  for (int i = tid; i < NPOINT * 3; i += FPS_THREADS) ob[i] = newb[i];
}

// ---------------- Ball query + group: one wave per query -------------------
// R23: 4-wide chunk-group scan. The old loop's per-chunk early exit
// (cnt<NSAMPLE) serialized load->ballot->branch->load, exposing ~200cy
// L2 latency per chunk; FPS picks extremal queries that scan MANY chunks.
// Now: issue 4 independent loads back-to-back, process the 4 chunks in
// original order, check exit per group. Bit-identical outputs: writes are
// gated by pos<NSAMPLE, cnt is only compared <NSAMPLE (monotone), 'first'
// is sticky -> up to 3 extra processed chunks are output-invisible.
__device__ __forceinline__ void write_slot(float* __restrict__ out,
                                           const float* __restrict__ base,
                                           int b, int qi, int s, int p,
                                           float4 r0, float qx, float qy,
                                           float qz) {
  float dx = __fsub_rn(r0.x, qx);
  float dy = __fsub_rn(r0.y, qy);
  float dz = __fsub_rn(r0.z, qz);
  size_t qs = (size_t)b * NPOINT + qi;
  out[OFF_IDX + qs * NSAMPLE + s] = (float)p;  // idx stored as float32
  float* g = out + OFF_GXYZ + (qs * NSAMPLE + s) * 3;
  g[0] = dx;
  g[1] = dy;
  g[2] = dz;
  const float* row = base + (size_t)p * CH;
  float4 r1 = *reinterpret_cast<const float4*>(row + 4);
  float4 r2 = *reinterpret_cast<const float4*>(row + 8);
  float4 r3 = *reinterpret_cast<const float4*>(row + 12);
  float* np_ = out + OFF_NEWPTS + (qs * NSAMPLE + s) * CH;
  *reinterpret_cast<float4*>(np_ + 0) = make_float4(dx, dy, dz, r0.w);
  *reinterpret_cast<float4*>(np_ + 4) = r1;
  *reinterpret_cast<float4*>(np_ + 8) = r2;
  *reinterpret_cast<float4*>(np_ + 12) = r3;
}

__global__ __launch_bounds__(256) void ballq_kernel(
    const float* __restrict__ in, float* __restrict__ out) {
  const int lane = threadIdx.x & 63;
  const int qid = blockIdx.x * 4 + (threadIdx.x >> 6);
  const int b = qid >> 11;    // / NPOINT
  const int qi = qid & 2047;  // % NPOINT
  const float* base = in + (size_t)b * NPTS * CH;
  const float* q = out + OFF_NEWXYZ + ((size_t)b * NPOINT + qi) * 3;
  float qx = q[0], qy = q[1], qz = q[2];
  // Mirror reference: d2 = sum(q*q) + sum(p*p) - 2*(q . p)
  float qn = __fadd_rn(__fadd_rn(__fmul_rn(qx, qx), __fmul_rn(qy, qy)),
                       __fmul_rn(qz, qz));

  int cnt = 0;
  int first = 0;
  bool have_first = false;
  for (int cg = 0; cg < NPTS / 64 && cnt < NSAMPLE; cg += 4) {
    // 4 independent loads issued back-to-back: one latency window per group.
    float4 r[4];
#pragma unroll
    for (int u = 0; u < 4; ++u)
      r[u] = *reinterpret_cast<const float4*>(
          base + (size_t)((cg + u) * 64 + lane) * CH);
    // Process the 4 chunks in original order (outputs bit-identical).
#pragma unroll
    for (int u = 0; u < 4; ++u) {
      const int chunk = cg + u;
      const int p = chunk * 64 + lane;
      const float4 r0 = r[u];
      float pn =
          __fadd_rn(__fadd_rn(__fmul_rn(r0.x, r0.x), __fmul_rn(r0.y, r0.y)),
                    __fmul_rn(r0.z, r0.z));
      float dot =
          __fadd_rn(__fadd_rn(__fmul_rn(qx, r0.x), __fmul_rn(qy, r0.y)),
                    __fmul_rn(qz, r0.z));
      float d2 = __fsub_rn(__fadd_rn(qn, pn), __fmul_rn(2.0f, dot));
      bool in_r = d2 < 1.0f;  // RADIUS^2
      unsigned long long mask = __ballot(in_r);
      if (!have_first && mask) {
        first = chunk * 64 + __builtin_ctzll(mask);
        have_first = true;
      }
      int pos = cnt + __popcll(mask & ((1ull << lane) - 1ull));
      if (in_r && pos < NSAMPLE)
        write_slot(out, base, b, qi, pos, p, r0, qx, qy, qz);
      cnt += __popcll(mask);
    }
  }
  if (cnt < NSAMPLE) {
    // Pad remaining slots with the first in-radius index (reference fill rule).
    int s = cnt + lane;
    if (s < NSAMPLE) {
      float4 r0 = *reinterpret_cast<const float4*>(base + (size_t)first * CH);
      write_slot(out, base, b, qi, s, first, r0, qx, qy, qz);
    }
  }
}

extern "C" void kernel_launch(void* const* d_in, const int* in_sizes, int n_in,
                              void* d_out, int out_size, void* d_ws,
                              size_t ws_size, hipStream_t stream) {
  (void)in_sizes;
  (void)n_in;
  (void)out_size;
  (void)d_ws;
  (void)ws_size;
  const float* in = (const float*)d_in[0];
  float* out = (float*)d_out;
  fps_kernel<<<NB, FPS_THREADS, 0, stream>>>(in, out);
  ballq_kernel<<<(NB * NPOINT) / 4, 256, 0, stream>>>(in, out);
}